// Round 1
// 257.201 us; speedup vs baseline: 1.0457x; 1.0457x over previous
//
#include <hip/hip_runtime.h>
#include <math.h>

// TrimSilence: WIN=32000, HOP=4000, OFF=8000, K=256, SEG=16000, T=40e6 @ f32.
//
// Ranking must match XLA's radix-16 two-phase cumsum association EXACTLY
// (means are differences of ~3e7-magnitude f32 cumsums; ulp ~2-4 there is
// larger than the rank-256 gap). Intra-4000-block sum order is irrelevant
// (prior session r1/r2/r4: block-sum tree changes gave identical results;
// block-sum perturbations ~1e-3 are far below ulp(3e7) so rounded cumsum
// values don't move). Means=(bc[i+8]-bc[i])/32000 f32, exact top-256
// (ties -> lowest index), centers ascending, f64-linspace fade.

#define T_LEN  40000000
#define HOP    4000
#define NBLK   10000      // T/HOP
#define NWIN   9993       // (T-WIN)/HOP + 1
#define KSEL   256
#define SEG    16000
#define OFF    8000

// ---- K1: per-4000-block |x| sums, float4 loads (G13) -----------------------
// 8 lanes per row, each reads 125 float4 (stride 8): 128 B contiguous per
// 8-lane group per iteration. 16 rows per 128-thread block, grid = 625.
__global__ __launch_bounds__(128) void k_blocksums(const float* __restrict__ in,
                                                   float* __restrict__ blocks) {
    const int g   = threadIdx.x >> 3;              // row group in block: 0..15
    const int j   = threadIdx.x & 7;
    const int row = blockIdx.x * 16 + g;           // 0..9999
    const float4* p = (const float4*)(in + (size_t)row * HOP) + j;
    float ax = 0.0f, ay = 0.0f, az = 0.0f, aw = 0.0f;  // 4 chains: shorter dep
    #pragma unroll 5
    for (int i = 0; i < 125; ++i) {
        const float4 x = p[(size_t)i * 8];
        ax += fabsf(x.x); ay += fabsf(x.y); az += fabsf(x.z); aw += fabsf(x.w);
    }
    float acc = (ax + ay) + (az + aw);
    acc += __shfl_xor(acc, 4);                     // reduce within 8-lane group
    acc += __shfl_xor(acc, 2);
    acc += __shfl_xor(acc, 1);
    if (j == 0) blocks[row] = acc;
}

// ---- K2: radix-16 cumsum, means in REGISTERS, top-256, ordered compact -----
__global__ __launch_bounds__(1024) void k_select(const float* __restrict__ blocks,
                                                 int* __restrict__ sel) {
    __shared__ float sb[NBLK];          // x -> inner0 scans -> cs (in place)
    __shared__ float s0[625];           // level-0 block sums
    __shared__ float w1[640];           // level-1 inner scans
    __shared__ float s1[40];            // level-1 block sums
    __shared__ float w2[48];            // level-2 inner scans
    __shared__ float s2[3];             // level-2 block sums
    __shared__ float p3[3];             // level-3 exclusive scan
    __shared__ float p2s[40];           // scan of s1
    __shared__ float p1s[625];          // scan of s0
    __shared__ unsigned whist[16][257]; // per-wave hist, +1 pad: 16 waves'
                                        // same-bin slots -> 16 distinct banks
    __shared__ unsigned hist[256];
    __shared__ unsigned rw[4];          // 4 wave-sums for 256-bin suffix scan
    __shared__ unsigned wsum[16];       // 16 wave-sums for compaction scan
    __shared__ unsigned s_pfx, s_k;
    const int tid  = threadIdx.x;
    const int lane = tid & 63;
    const int wid  = tid >> 6;

    for (int i = tid; i < NBLK; i += 1024) sb[i] = blocks[i];
    __syncthreads();

    // level-0 inner: sequential scan within each 16-block (in place)
    if (tid < 625) {
        const int base = tid * 16;
        float s = sb[base];
        #pragma unroll
        for (int j = 1; j < 16; ++j) { s += sb[base + j]; sb[base + j] = s; }
        s0[tid] = s;
    }
    __syncthreads();
    // level-1 inner: sequential scan of s0 within 16-blocks (block 39: 1 elem)
    if (tid < 40) {
        const int base = tid * 16;
        const int cnt1 = (tid == 39) ? 1 : 16;
        float s = s0[base];
        w1[base] = s;
        for (int j = 1; j < cnt1; ++j) { s += s0[base + j]; w1[base + j] = s; }
        s1[tid] = s;
    }
    __syncthreads();
    // level-2 inner: sequential scan of s1 within 16-blocks (block 2: 8 elems)
    if (tid < 3) {
        const int base = tid * 16;
        const int cnt2 = (tid == 2) ? 8 : 16;
        float s = s1[base];
        w2[base] = s;
        for (int j = 1; j < cnt2; ++j) { s += s1[base + j]; w2[base + j] = s; }
        s2[tid] = s;
    }
    __syncthreads();
    // level-3: sequential scan of 3, exclusive
    if (tid == 0) {
        p3[0] = 0.0f;
        p3[1] = s2[0];
        p3[2] = s2[0] + s2[1];
        s_pfx = 0u; s_k = KSEL;
    }
    __syncthreads();
    if (tid < 40) p2s[tid] = p3[tid >> 4] + w2[tid];
    __syncthreads();
    if (tid < 625) {
        const int c = tid >> 4;
        const float P2 = (c == 0) ? 0.0f : p2s[c - 1];
        p1s[tid] = P2 + w1[tid];
    }
    __syncthreads();
    for (int i = tid; i < NBLK; i += 1024) {
        const int b = i >> 4;
        const float P1 = (b == 0) ? 0.0f : p1s[b - 1];
        sb[i] = P1 + sb[i];
    }
    __syncthreads();

    // means[i] = (cs[i+7]-cs[i-1])/32000, cs[-1]=0 — each thread OWNS 10
    // consecutive windows, kept in registers (statically indexed: rule #20).
    const int lo  = tid * 10;
    const int cnt = (lo < NWIN) ? ((lo + 10 <= NWIN) ? 10 : NWIN - lo) : 0;
    unsigned uv[10];
    #pragma unroll
    for (int r = 0; r < 10; ++r) {
        if (r < cnt) {
            const int i = lo + r;
            const float lof = (i == 0) ? 0.0f : sb[i - 1];
            const float m = (sb[i + 7] - lof) / 32000.0f;
            uv[r] = __float_as_uint(m);   // positive f32 -> orderable uint
        }
    }

    // 4-pass 8-bit radix select for the 256th-largest value C.
    // Per-wave histograms: means cluster near 0.8 so passes 0/1 hit 1-10
    // bins; shared-hist atomics would serialize ~10k deep. 16 padded rows
    // cut that 16x.
    for (int pass = 0; pass < 4; ++pass) {
        const int shift = 24 - pass * 8;
        for (int i = tid; i < 16 * 257; i += 1024) ((unsigned*)whist)[i] = 0u;
        __syncthreads();
        const unsigned pfx  = s_pfx;
        const unsigned kcur = s_k;
        #pragma unroll
        for (int r = 0; r < 10; ++r) {
            if (r < cnt) {
                const unsigned u = uv[r];
                const bool cand = (pass == 0) || ((u >> (shift + 8)) == pfx);
                if (cand) atomicAdd(&whist[wid][(u >> shift) & 255u], 1u);
            }
        }
        __syncthreads();
        if (tid < 256) {
            unsigned s = 0;
            #pragma unroll
            for (int w = 0; w < 16; ++w) s += whist[w][tid];
            hist[tid] = s;
        }
        __syncthreads();
        // parallel suffix scan over 256 bins: thread tid handles bin 255-tid,
        // inclusive shfl scan over ascending tid == descending bins.
        unsigned inc = 0, h = 0;
        if (tid < 256) {                 // waves 0..3 exactly — no divergence
            h = hist[255 - tid];
            inc = h;
            #pragma unroll
            for (int o = 1; o < 64; o <<= 1) {
                const unsigned n = __shfl_up(inc, o);
                if (lane >= o) inc += n;
            }
            if (lane == 63) rw[tid >> 6] = inc;
        }
        __syncthreads();
        if (tid < 256) {
            unsigned add = 0;
            for (int k = 0; k < (tid >> 6); ++k) add += rw[k];
            const unsigned suf   = inc + add;    // candidates in bins >= b
            const unsigned above = suf - h;      // strictly higher bins
            if (suf >= kcur && above < kcur) {   // exactly one bin matches
                s_pfx = (pfx << 8) | (unsigned)(255 - tid);
                s_k   = kcur - above;
            }
        }
        __syncthreads();
    }
    const unsigned C   = s_pfx;   // 256th-largest mean (bits)
    const unsigned keq = s_k;     // how many ==C to keep (lowest index first)

    // ordered compaction from registers; packed (eq | gt<<16) shfl scan.
    unsigned ceq = 0, cgt = 0;
    #pragma unroll
    for (int r = 0; r < 10; ++r) {
        if (r < cnt) {
            const unsigned u = uv[r];
            cgt += (u > C)  ? 1u : 0u;
            ceq += (u == C) ? 1u : 0u;
        }
    }
    const unsigned pack = ceq | (cgt << 16);     // sums < 2^16 each: no carry
    unsigned incp = pack;
    #pragma unroll
    for (int o = 1; o < 64; o <<= 1) {
        const unsigned n = __shfl_up(incp, o);
        if (lane >= o) incp += n;
    }
    if (lane == 63) wsum[wid] = incp;
    __syncthreads();
    unsigned woffv = 0;
    for (int w = 0; w < wid; ++w) woffv += wsum[w];   // broadcast reads
    const unsigned ex = incp - pack + woffv;          // exclusive prefix
    unsigned e = ex & 0xFFFFu;    // #eq strictly before my range
    unsigned g = ex >> 16;        // #gt strictly before my range
    #pragma unroll
    for (int r = 0; r < 10; ++r) {
        if (r < cnt) {
            const unsigned u = uv[r];
            if (u > C) {
                const unsigned esel = (e < keq) ? e : keq;
                sel[g + esel] = lo + r;   // slot = #selected before i
                ++g;
            } else if (u == C) {
                if (e < keq) sel[g + e] = lo + r;
                ++e;
            }
        }
    }
}

// ---- K3: gather 256 segments x 16000, apply linspace fade mask -------------
__global__ __launch_bounds__(256) void k_gather(const float* __restrict__ in,
                                                const int* __restrict__ sel,
                                                float* __restrict__ out) {
    const int b = blockIdx.x;
    const int s = b >> 2;          // segment 0..255
    const int part = b & 3;        // quarter of the segment
    const int w = sel[s];          // window index (ascending across s)
    const float4* ip = (const float4*)(in + (size_t)w * HOP + OFF);
    float4* op = (float4*)(out + (size_t)s * SEG);
    const double st = 1.0 / 15999.0;   // np.linspace step (f64), last elem = 1
    const int v0 = part * 1000;
    for (int v = v0 + threadIdx.x; v < v0 + 1000; v += 256) {
        float4 x = ip[v];
        int jj = v * 4;
        float t0 = (float)(jj * st);
        float t1 = (float)((jj + 1) * st);
        float t2 = (float)((jj + 2) * st);
        float t3 = (jj + 3 == 15999) ? 1.0f : (float)((jj + 3) * st);
        x.x *= t0 * (1.0f - t0);
        x.y *= t1 * (1.0f - t1);
        x.z *= t2 * (1.0f - t2);
        x.w *= t3 * (1.0f - t3);
        op[v] = x;
    }
}

extern "C" void kernel_launch(void* const* d_in, const int* in_sizes, int n_in,
                              void* d_out, int out_size, void* d_ws, size_t ws_size,
                              hipStream_t stream) {
    (void)in_sizes; (void)n_in; (void)out_size; (void)ws_size;
    const float* in = (const float*)d_in[0];
    float* out = (float*)d_out;
    char* ws = (char*)d_ws;
    float* blocks = (float*)ws;                    // 10000 f32 @ 0
    int*   sel    = (int*)(ws + 40960);            // 256   i32
    k_blocksums<<<dim3(625), dim3(128), 0, stream>>>(in, blocks);
    k_select<<<dim3(1), dim3(1024), 0, stream>>>(blocks, sel);
    k_gather<<<dim3(KSEL * 4), dim3(256), 0, stream>>>(in, sel, out);
}

// Round 2
// 253.866 us; speedup vs baseline: 1.0594x; 1.0131x over previous
//
#include <hip/hip_runtime.h>
#include <math.h>

// TrimSilence: WIN=32000, HOP=4000, OFF=8000, K=256, SEG=16000, T=40e6 @ f32.
//
// Ranking must match XLA's radix-16 two-phase cumsum association EXACTLY
// (means are differences of ~3e7-magnitude f32 cumsums; ulp ~2-4 there is
// larger than the rank-256 gap). Intra-4000-block sum order is irrelevant
// (prior rounds used different intra-row trees, identical results;
// block-sum perturbations ~1e-3 are far below ulp(3e7) so rounded cumsum
// values don't move). Means=(bc[i+8]-bc[i])/32000 f32, exact top-256
// (ties -> lowest index), centers ascending, f64-linspace fade.

#define T_LEN  40000000
#define HOP    4000
#define NBLK   10000      // T/HOP
#define NWIN   9993       // (T-WIN)/HOP + 1
#define KSEL   256
#define SEG    16000
#define OFF    8000

// ---- K1: per-4000-block |x| sums, one wave per row -------------------------
// Row = 1000 float4. Lane j sums float4[j + 64*i], i=0..14 (960), plus a
// 40-lane tail for [960..999]. 4 rows per 256-thread block, grid = 2500:
// 10000 waves ~ 39 waves/CU queued -> enough TLP to hide HBM latency
// (round-1's 625x128 layout gave only ~1.2 waves/SIMD -> BW-starved).
__global__ __launch_bounds__(256) void k_blocksums(const float* __restrict__ in,
                                                   float* __restrict__ blocks) {
    const int wave = threadIdx.x >> 6;             // 0..3
    const int lane = threadIdx.x & 63;
    const int row  = blockIdx.x * 4 + wave;        // 0..9999
    const float4* p = (const float4*)(in + (size_t)row * HOP);
    float acc = 0.0f;
    #pragma unroll
    for (int i = 0; i < 15; ++i) {
        const float4 x = p[lane + i * 64];
        acc += (fabsf(x.x) + fabsf(x.y)) + (fabsf(x.z) + fabsf(x.w));
    }
    if (lane < 40) {
        const float4 x = p[960 + lane];
        acc += (fabsf(x.x) + fabsf(x.y)) + (fabsf(x.z) + fabsf(x.w));
    }
    acc += __shfl_xor(acc, 32);
    acc += __shfl_xor(acc, 16);
    acc += __shfl_xor(acc, 8);
    acc += __shfl_xor(acc, 4);
    acc += __shfl_xor(acc, 2);
    acc += __shfl_xor(acc, 1);
    if (lane == 0) blocks[row] = acc;
}

// ---- K2: radix-16 cumsum, means in REGISTERS, top-256, ordered compact -----
__global__ __launch_bounds__(1024) void k_select(const float* __restrict__ blocks,
                                                 int* __restrict__ sel) {
    __shared__ float sb[NBLK];          // x -> inner0 scans -> cs (in place)
    __shared__ float s0[625];           // level-0 block sums
    __shared__ float w1[640];           // level-1 inner scans
    __shared__ float s1[40];            // level-1 block sums
    __shared__ float w2[48];            // level-2 inner scans
    __shared__ float s2[3];             // level-2 block sums
    __shared__ float p3[3];             // level-3 exclusive scan
    __shared__ float p2s[40];           // scan of s1
    __shared__ float p1s[625];          // scan of s0
    __shared__ unsigned whist[16][257]; // per-wave hist, +1 pad: 16 waves'
                                        // same-bin slots -> 16 distinct banks
    __shared__ unsigned hist[256];
    __shared__ unsigned rw[4];          // 4 wave-sums for 256-bin suffix scan
    __shared__ unsigned wsum[16];       // 16 wave-sums for compaction scan
    __shared__ unsigned s_pfx, s_k;
    const int tid  = threadIdx.x;
    const int lane = tid & 63;
    const int wid  = tid >> 6;

    for (int i = tid; i < NBLK; i += 1024) sb[i] = blocks[i];
    __syncthreads();

    // level-0 inner: sequential scan within each 16-block (in place)
    if (tid < 625) {
        const int base = tid * 16;
        float s = sb[base];
        #pragma unroll
        for (int j = 1; j < 16; ++j) { s += sb[base + j]; sb[base + j] = s; }
        s0[tid] = s;
    }
    __syncthreads();
    // level-1 inner: sequential scan of s0 within 16-blocks (block 39: 1 elem)
    if (tid < 40) {
        const int base = tid * 16;
        const int cnt1 = (tid == 39) ? 1 : 16;
        float s = s0[base];
        w1[base] = s;
        for (int j = 1; j < cnt1; ++j) { s += s0[base + j]; w1[base + j] = s; }
        s1[tid] = s;
    }
    __syncthreads();
    // level-2 inner: sequential scan of s1 within 16-blocks (block 2: 8 elems)
    if (tid < 3) {
        const int base = tid * 16;
        const int cnt2 = (tid == 2) ? 8 : 16;
        float s = s1[base];
        w2[base] = s;
        for (int j = 1; j < cnt2; ++j) { s += s1[base + j]; w2[base + j] = s; }
        s2[tid] = s;
    }
    __syncthreads();
    // level-3: sequential scan of 3, exclusive
    if (tid == 0) {
        p3[0] = 0.0f;
        p3[1] = s2[0];
        p3[2] = s2[0] + s2[1];
        s_pfx = 0u; s_k = KSEL;
    }
    __syncthreads();
    if (tid < 40) p2s[tid] = p3[tid >> 4] + w2[tid];
    __syncthreads();
    if (tid < 625) {
        const int c = tid >> 4;
        const float P2 = (c == 0) ? 0.0f : p2s[c - 1];
        p1s[tid] = P2 + w1[tid];
    }
    __syncthreads();
    for (int i = tid; i < NBLK; i += 1024) {
        const int b = i >> 4;
        const float P1 = (b == 0) ? 0.0f : p1s[b - 1];
        sb[i] = P1 + sb[i];
    }
    __syncthreads();

    // means[i] = (cs[i+7]-cs[i-1])/32000, cs[-1]=0 — each thread OWNS 10
    // consecutive windows, kept in registers (statically indexed: rule #20).
    const int lo  = tid * 10;
    const int cnt = (lo < NWIN) ? ((lo + 10 <= NWIN) ? 10 : NWIN - lo) : 0;
    unsigned uv[10];
    #pragma unroll
    for (int r = 0; r < 10; ++r) {
        if (r < cnt) {
            const int i = lo + r;
            const float lof = (i == 0) ? 0.0f : sb[i - 1];
            const float m = (sb[i + 7] - lof) / 32000.0f;
            uv[r] = __float_as_uint(m);   // positive f32 -> orderable uint
        }
    }

    // 4-pass 8-bit radix select for the 256th-largest value C.
    // Per-wave histograms: means cluster near 0.8 so passes 0/1 hit 1-10
    // bins; shared-hist atomics would serialize ~10k deep. 16 padded rows
    // cut that 16x.
    for (int pass = 0; pass < 4; ++pass) {
        const int shift = 24 - pass * 8;
        for (int i = tid; i < 16 * 257; i += 1024) ((unsigned*)whist)[i] = 0u;
        __syncthreads();
        const unsigned pfx  = s_pfx;
        const unsigned kcur = s_k;
        #pragma unroll
        for (int r = 0; r < 10; ++r) {
            if (r < cnt) {
                const unsigned u = uv[r];
                const bool cand = (pass == 0) || ((u >> (shift + 8)) == pfx);
                if (cand) atomicAdd(&whist[wid][(u >> shift) & 255u], 1u);
            }
        }
        __syncthreads();
        if (tid < 256) {
            unsigned s = 0;
            #pragma unroll
            for (int w = 0; w < 16; ++w) s += whist[w][tid];
            hist[tid] = s;
        }
        __syncthreads();
        // parallel suffix scan over 256 bins: thread tid handles bin 255-tid,
        // inclusive shfl scan over ascending tid == descending bins.
        unsigned inc = 0, h = 0;
        if (tid < 256) {                 // waves 0..3 exactly — no divergence
            h = hist[255 - tid];
            inc = h;
            #pragma unroll
            for (int o = 1; o < 64; o <<= 1) {
                const unsigned n = __shfl_up(inc, o);
                if (lane >= o) inc += n;
            }
            if (lane == 63) rw[tid >> 6] = inc;
        }
        __syncthreads();
        if (tid < 256) {
            unsigned add = 0;
            for (int k = 0; k < (tid >> 6); ++k) add += rw[k];
            const unsigned suf   = inc + add;    // candidates in bins >= b
            const unsigned above = suf - h;      // strictly higher bins
            if (suf >= kcur && above < kcur) {   // exactly one bin matches
                s_pfx = (pfx << 8) | (unsigned)(255 - tid);
                s_k   = kcur - above;
            }
        }
        __syncthreads();
    }
    const unsigned C   = s_pfx;   // 256th-largest mean (bits)
    const unsigned keq = s_k;     // how many ==C to keep (lowest index first)

    // ordered compaction from registers; packed (eq | gt<<16) shfl scan.
    unsigned ceq = 0, cgt = 0;
    #pragma unroll
    for (int r = 0; r < 10; ++r) {
        if (r < cnt) {
            const unsigned u = uv[r];
            cgt += (u > C)  ? 1u : 0u;
            ceq += (u == C) ? 1u : 0u;
        }
    }
    const unsigned pack = ceq | (cgt << 16);     // sums < 2^16 each: no carry
    unsigned incp = pack;
    #pragma unroll
    for (int o = 1; o < 64; o <<= 1) {
        const unsigned n = __shfl_up(incp, o);
        if (lane >= o) incp += n;
    }
    if (lane == 63) wsum[wid] = incp;
    __syncthreads();
    unsigned woffv = 0;
    for (int w = 0; w < wid; ++w) woffv += wsum[w];   // broadcast reads
    const unsigned ex = incp - pack + woffv;          // exclusive prefix
    unsigned e = ex & 0xFFFFu;    // #eq strictly before my range
    unsigned g = ex >> 16;        // #gt strictly before my range
    #pragma unroll
    for (int r = 0; r < 10; ++r) {
        if (r < cnt) {
            const unsigned u = uv[r];
            if (u > C) {
                const unsigned esel = (e < keq) ? e : keq;
                sel[g + esel] = lo + r;   // slot = #selected before i
                ++g;
            } else if (u == C) {
                if (e < keq) sel[g + e] = lo + r;
                ++e;
            }
        }
    }
}

// ---- K3: gather 256 segments x 16000, apply linspace fade mask -------------
__global__ __launch_bounds__(256) void k_gather(const float* __restrict__ in,
                                                const int* __restrict__ sel,
                                                float* __restrict__ out) {
    const int b = blockIdx.x;
    const int s = b >> 2;          // segment 0..255
    const int part = b & 3;        // quarter of the segment
    const int w = sel[s];          // window index (ascending across s)
    const float4* ip = (const float4*)(in + (size_t)w * HOP + OFF);
    float4* op = (float4*)(out + (size_t)s * SEG);
    const double st = 1.0 / 15999.0;   // np.linspace step (f64), last elem = 1
    const int v0 = part * 1000;
    for (int v = v0 + threadIdx.x; v < v0 + 1000; v += 256) {
        float4 x = ip[v];
        int jj = v * 4;
        float t0 = (float)(jj * st);
        float t1 = (float)((jj + 1) * st);
        float t2 = (float)((jj + 2) * st);
        float t3 = (jj + 3 == 15999) ? 1.0f : (float)((jj + 3) * st);
        x.x *= t0 * (1.0f - t0);
        x.y *= t1 * (1.0f - t1);
        x.z *= t2 * (1.0f - t2);
        x.w *= t3 * (1.0f - t3);
        op[v] = x;
    }
}

extern "C" void kernel_launch(void* const* d_in, const int* in_sizes, int n_in,
                              void* d_out, int out_size, void* d_ws, size_t ws_size,
                              hipStream_t stream) {
    (void)in_sizes; (void)n_in; (void)out_size; (void)ws_size;
    const float* in = (const float*)d_in[0];
    float* out = (float*)d_out;
    char* ws = (char*)d_ws;
    float* blocks = (float*)ws;                    // 10000 f32 @ 0
    int*   sel    = (int*)(ws + 40960);            // 256   i32
    k_blocksums<<<dim3(2500), dim3(256), 0, stream>>>(in, blocks);
    k_select<<<dim3(1), dim3(1024), 0, stream>>>(blocks, sel);
    k_gather<<<dim3(KSEL * 4), dim3(256), 0, stream>>>(in, sel, out);
}

// Round 3
// 242.450 us; speedup vs baseline: 1.1093x; 1.0471x over previous
//
#include <hip/hip_runtime.h>
#include <math.h>

// TrimSilence: WIN=32000, HOP=4000, OFF=8000, K=256, SEG=16000, T=40e6 @ f32.
//
// Ranking must match XLA's radix-16 two-phase cumsum association EXACTLY
// (means are differences of ~3e7-magnitude f32 cumsums; ulp ~2-4 there is
// larger than the rank-256 gap). Intra-4000-block sum order is irrelevant
// (prior rounds used different intra-row trees, identical results).
// Means=(bc[i+8]-bc[i])/32000 f32, exact top-256 (ties -> lowest index),
// centers ascending, f64-linspace fade.
//
// Round-3: keys cluster (mean 0.798, sigma 0.43% relative) -> top ~14 bits
// identical -> byte-aligned radix passes 0/1 were degenerate (all keys in
// 1 bin: ~10k serialized same-address LDS atomics each). Now: min/max
// reduce first, then radix windows anchored at the top discriminating bit
// -> first pass spreads across up to 256 bins by construction; ~3 passes,
// none degenerate. Bit-identical selection.

#define T_LEN  40000000
#define HOP    4000
#define NBLK   10000      // T/HOP
#define NWIN   9993       // (T-WIN)/HOP + 1
#define KSEL   256
#define SEG    16000
#define OFF    8000

// ---- K1: per-4000-block |x| sums, one wave per row (HBM-floor bound) -------
__global__ __launch_bounds__(256) void k_blocksums(const float* __restrict__ in,
                                                   float* __restrict__ blocks) {
    const int wave = threadIdx.x >> 6;             // 0..3
    const int lane = threadIdx.x & 63;
    const int row  = blockIdx.x * 4 + wave;        // 0..9999
    const float4* p = (const float4*)(in + (size_t)row * HOP);
    float acc = 0.0f;
    #pragma unroll
    for (int i = 0; i < 15; ++i) {
        const float4 x = p[lane + i * 64];
        acc += (fabsf(x.x) + fabsf(x.y)) + (fabsf(x.z) + fabsf(x.w));
    }
    if (lane < 40) {
        const float4 x = p[960 + lane];
        acc += (fabsf(x.x) + fabsf(x.y)) + (fabsf(x.z) + fabsf(x.w));
    }
    acc += __shfl_xor(acc, 32);
    acc += __shfl_xor(acc, 16);
    acc += __shfl_xor(acc, 8);
    acc += __shfl_xor(acc, 4);
    acc += __shfl_xor(acc, 2);
    acc += __shfl_xor(acc, 1);
    if (lane == 0) blocks[row] = acc;
}

// ---- K2: radix-16 cumsum, means in registers, range-anchored top-256 -------
__global__ __launch_bounds__(1024) void k_select(const float* __restrict__ blocks,
                                                 int* __restrict__ sel) {
    __shared__ float sb[NBLK];          // x -> inner0 scans -> cs (in place)
    __shared__ float s0[625];           // level-0 block sums
    __shared__ float w1[640];           // level-1 inner scans
    __shared__ float s1[40];            // level-1 block sums
    __shared__ float w2[48];            // level-2 inner scans
    __shared__ float s2[3];             // level-2 block sums
    __shared__ float p3[3];             // level-3 exclusive scan
    __shared__ float p2s[40];           // scan of s1
    __shared__ float p1s[625];          // scan of s0
    __shared__ unsigned whist[16][257]; // per-wave hist, +1 pad -> bank spread
    __shared__ unsigned hist[256];
    __shared__ unsigned rw[4];          // 4 wave-sums for 256-bin suffix scan
    __shared__ unsigned wsum[16];       // 16 wave-sums (compaction / minmax)
    __shared__ unsigned smn[16], smx[16];
    __shared__ unsigned s_pfx, s_k, s_mn, s_mx;
    const int tid  = threadIdx.x;
    const int lane = tid & 63;
    const int wid  = tid >> 6;

    for (int i = tid; i < NBLK; i += 1024) sb[i] = blocks[i];
    __syncthreads();

    // level-0 inner: sequential scan within each 16-block (in place)
    if (tid < 625) {
        const int base = tid * 16;
        float s = sb[base];
        #pragma unroll
        for (int j = 1; j < 16; ++j) { s += sb[base + j]; sb[base + j] = s; }
        s0[tid] = s;
    }
    __syncthreads();
    // level-1 inner: sequential scan of s0 within 16-blocks (block 39: 1 elem)
    if (tid < 40) {
        const int base = tid * 16;
        const int cnt1 = (tid == 39) ? 1 : 16;
        float s = s0[base];
        w1[base] = s;
        for (int j = 1; j < cnt1; ++j) { s += s0[base + j]; w1[base + j] = s; }
        s1[tid] = s;
    }
    __syncthreads();
    // level-2 inner: sequential scan of s1 within 16-blocks (block 2: 8 elems)
    if (tid < 3) {
        const int base = tid * 16;
        const int cnt2 = (tid == 2) ? 8 : 16;
        float s = s1[base];
        w2[base] = s;
        for (int j = 1; j < cnt2; ++j) { s += s1[base + j]; w2[base + j] = s; }
        s2[tid] = s;
    }
    __syncthreads();
    // level-3: sequential scan of 3, exclusive
    if (tid == 0) {
        p3[0] = 0.0f;
        p3[1] = s2[0];
        p3[2] = s2[0] + s2[1];
        s_k = KSEL;
    }
    __syncthreads();
    if (tid < 40) p2s[tid] = p3[tid >> 4] + w2[tid];
    __syncthreads();
    if (tid < 625) {
        const int c = tid >> 4;
        const float P2 = (c == 0) ? 0.0f : p2s[c - 1];
        p1s[tid] = P2 + w1[tid];
    }
    __syncthreads();
    for (int i = tid; i < NBLK; i += 1024) {
        const int b = i >> 4;
        const float P1 = (b == 0) ? 0.0f : p1s[b - 1];
        sb[i] = P1 + sb[i];
    }
    __syncthreads();

    // means[i] = (cs[i+7]-cs[i-1])/32000, cs[-1]=0 — each thread OWNS 10
    // consecutive windows, kept in registers (statically indexed: rule #20).
    const int lo  = tid * 10;
    const int cnt = (lo < NWIN) ? ((lo + 10 <= NWIN) ? 10 : NWIN - lo) : 0;
    unsigned uv[10];
    unsigned mn = 0xFFFFFFFFu, mx = 0u;
    #pragma unroll
    for (int r = 0; r < 10; ++r) {
        if (r < cnt) {
            const int i = lo + r;
            const float lof = (i == 0) ? 0.0f : sb[i - 1];
            const float m = (sb[i + 7] - lof) / 32000.0f;
            const unsigned u = __float_as_uint(m);  // positive f32 orderable
            uv[r] = u;
            mn = (u < mn) ? u : mn;
            mx = (u > mx) ? u : mx;
        }
    }
    // global min/max of keys (for range-anchored radix windows)
    #pragma unroll
    for (int o = 32; o >= 1; o >>= 1) {
        const unsigned a = __shfl_xor(mn, o);
        const unsigned b = __shfl_xor(mx, o);
        mn = (a < mn) ? a : mn;
        mx = (b > mx) ? b : mx;
    }
    if (lane == 0) { smn[wid] = mn; smx[wid] = mx; }
    __syncthreads();
    if (tid == 0) {
        unsigned gmn = smn[0], gmx = smx[0];
        #pragma unroll
        for (int w = 1; w < 16; ++w) {
            gmn = (smn[w] < gmn) ? smn[w] : gmn;
            gmx = (smx[w] > gmx) ? smx[w] : gmx;
        }
        s_mn = gmn; s_mx = gmx;
        // init pfx to the common high bits (all keys agree above hibit)
        const unsigned diff = gmn ^ gmx;
        if (diff == 0u) {
            s_pfx = gmx;              // all keys equal: C = key, keq = 256
        } else {
            const int hibit = 31 - __clz(diff);   // <= 30 (keys positive)
            s_pfx = gmx >> (hibit + 1);
        }
    }
    __syncthreads();

    // radix select over bits [hibit:0], windows anchored at hibit.
    // Pass 1 window [hibit : hibit-7] -> keys split across many bins by
    // construction (top discriminating bit is the window MSB).
    const unsigned gdiff = s_mn ^ s_mx;
    if (gdiff != 0u) {
        int s = (31 - __clz(gdiff)) + 1;       // first un-agreed bit count
        for (;;) {
            const int ns = (s > 8) ? s - 8 : 0;
            const int w  = s - ns;             // window width 1..8
            for (int i = tid; i < 16 * 257; i += 1024) ((unsigned*)whist)[i] = 0u;
            __syncthreads();
            const unsigned pfx  = s_pfx;
            const unsigned kcur = s_k;
            const unsigned msk  = (w == 8) ? 255u : ((1u << w) - 1u);
            #pragma unroll
            for (int r = 0; r < 10; ++r) {
                if (r < cnt) {
                    const unsigned u = uv[r];
                    if ((u >> s) == pfx)
                        atomicAdd(&whist[wid][(u >> ns) & msk], 1u);
                }
            }
            __syncthreads();
            if (tid < 256) {
                unsigned acc = 0;
                #pragma unroll
                for (int ww = 0; ww < 16; ++ww) acc += whist[ww][tid];
                hist[tid] = acc;
            }
            __syncthreads();
            // parallel suffix scan over 256 bins (descending bin order)
            unsigned inc = 0, h = 0;
            if (tid < 256) {
                h = hist[255 - tid];
                inc = h;
                #pragma unroll
                for (int o = 1; o < 64; o <<= 1) {
                    const unsigned n = __shfl_up(inc, o);
                    if (lane >= o) inc += n;
                }
                if (lane == 63) rw[tid >> 6] = inc;
            }
            __syncthreads();
            if (tid < 256) {
                unsigned add = 0;
                for (int k = 0; k < (tid >> 6); ++k) add += rw[k];
                const unsigned suf   = inc + add;  // candidates in bins >= b
                const unsigned above = suf - h;    // strictly higher bins
                if (suf >= kcur && above < kcur) { // exactly one bin matches
                    s_pfx = (pfx << w) | (unsigned)(255 - tid);
                    s_k   = kcur - above;
                }
            }
            __syncthreads();
            if (ns == 0) break;
            s = ns;
        }
    }
    const unsigned C   = s_pfx;   // 256th-largest mean (bits)
    const unsigned keq = s_k;     // how many ==C to keep (lowest index first)

    // ordered compaction from registers; packed (eq | gt<<16) shfl scan.
    unsigned ceq = 0, cgt = 0;
    #pragma unroll
    for (int r = 0; r < 10; ++r) {
        if (r < cnt) {
            const unsigned u = uv[r];
            cgt += (u > C)  ? 1u : 0u;
            ceq += (u == C) ? 1u : 0u;
        }
    }
    const unsigned pack = ceq | (cgt << 16);     // sums < 2^16 each: no carry
    unsigned incp = pack;
    #pragma unroll
    for (int o = 1; o < 64; o <<= 1) {
        const unsigned n = __shfl_up(incp, o);
        if (lane >= o) incp += n;
    }
    if (lane == 63) wsum[wid] = incp;
    __syncthreads();
    unsigned woffv = 0;
    for (int w = 0; w < wid; ++w) woffv += wsum[w];   // broadcast reads
    const unsigned ex = incp - pack + woffv;          // exclusive prefix
    unsigned e = ex & 0xFFFFu;    // #eq strictly before my range
    unsigned g = ex >> 16;        // #gt strictly before my range
    #pragma unroll
    for (int r = 0; r < 10; ++r) {
        if (r < cnt) {
            const unsigned u = uv[r];
            if (u > C) {
                const unsigned esel = (e < keq) ? e : keq;
                sel[g + esel] = lo + r;   // slot = #selected before i
                ++g;
            } else if (u == C) {
                if (e < keq) sel[g + e] = lo + r;
                ++e;
            }
        }
    }
}

// ---- K3: gather 256 segments x 16000, apply linspace fade mask -------------
__global__ __launch_bounds__(256) void k_gather(const float* __restrict__ in,
                                                const int* __restrict__ sel,
                                                float* __restrict__ out) {
    const int b = blockIdx.x;
    const int s = b >> 2;          // segment 0..255
    const int part = b & 3;        // quarter of the segment
    const int w = sel[s];          // window index (ascending across s)
    const float4* ip = (const float4*)(in + (size_t)w * HOP + OFF);
    float4* op = (float4*)(out + (size_t)s * SEG);
    const double st = 1.0 / 15999.0;   // np.linspace step (f64), last elem = 1
    const int v0 = part * 1000;
    for (int v = v0 + threadIdx.x; v < v0 + 1000; v += 256) {
        float4 x = ip[v];
        int jj = v * 4;
        float t0 = (float)(jj * st);
        float t1 = (float)((jj + 1) * st);
        float t2 = (float)((jj + 2) * st);
        float t3 = (jj + 3 == 15999) ? 1.0f : (float)((jj + 3) * st);
        x.x *= t0 * (1.0f - t0);
        x.y *= t1 * (1.0f - t1);
        x.z *= t2 * (1.0f - t2);
        x.w *= t3 * (1.0f - t3);
        op[v] = x;
    }
}

extern "C" void kernel_launch(void* const* d_in, const int* in_sizes, int n_in,
                              void* d_out, int out_size, void* d_ws, size_t ws_size,
                              hipStream_t stream) {
    (void)in_sizes; (void)n_in; (void)out_size; (void)ws_size;
    const float* in = (const float*)d_in[0];
    float* out = (float*)d_out;
    char* ws = (char*)d_ws;
    float* blocks = (float*)ws;                    // 10000 f32 @ 0
    int*   sel    = (int*)(ws + 40960);            // 256   i32
    k_blocksums<<<dim3(2500), dim3(256), 0, stream>>>(in, blocks);
    k_select<<<dim3(1), dim3(1024), 0, stream>>>(blocks, sel);
    k_gather<<<dim3(KSEL * 4), dim3(256), 0, stream>>>(in, sel, out);
}